// Round 16
// baseline (42.257 us; speedup 1.0000x reference)
//
#include <hip/hip_runtime.h>
#include <stdint.h>

#define INPUT_SCALE 0.0078125f   // 2^-7

__device__ __forceinline__ uint32_t sadu8(uint32_t a, uint32_t b, uint32_t c) {
#if __has_builtin(__builtin_amdgcn_sad_u8)
    return __builtin_amdgcn_sad_u8(a, b, c);
#else
    uint32_t d;
    asm("v_sad_u8 %0, %1, %2, %3" : "=v"(d) : "v"(a), "v"(b), "v"(c));
    return d;
#endif
}

__device__ __forceinline__ uint32_t qbyte(float x) {
    // round(clip(x*128, -127, 127)) + 128  (rintf = round-half-even, matches jnp.round)
    float v = fminf(fmaxf(x * 128.0f, -127.0f), 127.0f);
    return (uint32_t)((int)rintf(v) + 128);
}

// ---------------- Kernel A: weight scale + pack, 9 blocks ----------------
// Tap-major: u = (t*32 + f)*8 + cg, t = kh*3+kw; one tap = 1 KB contiguous.
__global__ __launch_bounds__(256) void quant_weight(const float* __restrict__ w,
                                                    uint32_t* __restrict__ qwp) {
    __shared__ float red[256];
    __shared__ float s_inv;
    int tid = threadIdx.x;
    float m = 0.0f;
    for (int i = tid; i < 9216; i += 256) m = fmaxf(m, fabsf(w[i]));
    red[tid] = m;
    __syncthreads();
    for (int s = 128; s > 0; s >>= 1) {
        if (tid < s) red[tid] = fmaxf(red[tid], red[tid + s]);
        __syncthreads();
    }
    if (tid == 0) {
        float s = fmaxf(red[0] / 127.0f, 1e-8f);
        int e; float fr = frexpf(s, &e);            // s = fr * 2^e, fr in [0.5,1)
        int k = (fr >= 0.70710678118654752f) ? e : e - 1;  // round(log2(s))
        s_inv = exp2f((float)(-k));                 // 1/s_w, exact power of 2
    }
    __syncthreads();
    float inv = s_inv;
    int u = blockIdx.x * 256 + tid;                 // 9*256 = 2304 exactly
    {
        int t = u >> 8;            // tap 0..8
        int rem = u & 255;
        int f = rem >> 3, cg = rem & 7;
        int kh = t / 3, kw = t - kh * 3;
        uint32_t pk = 0;
        #pragma unroll
        for (int b = 0; b < 4; ++b) {
            int c = cg * 4 + b;
            float v = w[((f * 32 + c) * 3 + kh) * 3 + kw] * inv;
            v = fminf(fmaxf(v, -127.0f), 127.0f);
            pk |= ((uint32_t)((int)rintf(v) + 128) & 0xFFu) << (8 * b);
        }
        qwp[u] = pk;
    }
}

// ---------------- Kernel B: fused quantize + SAD conv ----------------
// R15 structure (tile 16x4, 256 thr = 64 px x 4 fg, 1-chunk/tap weights,
// grid 4096) + WAVE-ROTATED TAP ORDER: wave fg processes taps in order
// (2*fg + ti) mod 9. R15 showed VALUBusy pinned at 45% = one full lgkm
// latency exposed per tap: all resident waves ran the identical schedule
// lockstep (phase-locked), so no cross-wave hiding. Rotation offsets each
// wave's wait-points by ~1000 cy; the SAD sum is tap-order-independent.
#define LSTRIDE 12  // u32 per pixel slot (32B data + 16B pad)
__global__ __launch_bounds__(256, 8) void adder_conv_fused(const float* __restrict__ x,
                                                           const uint32_t* __restrict__ qwp,
                                                           float* __restrict__ out) {
    __shared__ __align__(16) uint32_t sx[6 * 18 * LSTRIDE];   // 5184 B
    int tid = threadIdx.x;
    // XCD-contiguous remap: XCD k owns 512 consecutive tiles (2 images).
    int b = ((blockIdx.x & 7) << 9) + (blockIdx.x >> 3);
    int n = b >> 8;                 // image 0..15
    int rem = b & 255;              // tile in image (32 rows x 8 cols)
    int h0 = (rem >> 3) * 4, w0 = (rem & 7) * 16;

    // quantize + pack the 6x18 halo (32 ch -> 8 u32/pixel) into LDS.
    for (int q = tid; q < 864; q += 256) {           // 864 = 108 px * 8 cg
        int cg = q / 108;
        int pixel = q - cg * 108;
        int r = pixel / 18, cc = pixel - r * 18;
        int gh = h0 - 1 + r, gw = w0 - 1 + cc;
        uint32_t pk = 0x80808080u;                   // quantized-zero padding
        if ((unsigned)gh < 128u && (unsigned)gw < 128u) {
            const float* base = x + (((size_t)n * 32 + cg * 4) * 128 + gh) * 128 + gw;
            pk = qbyte(base[0])
               | (qbyte(base[16384]) << 8)
               | (qbyte(base[32768]) << 16)
               | (qbyte(base[49152]) << 24);
        }
        sx[pixel * LSTRIDE + cg] = pk;
    }
    __syncthreads();

    int fg = __builtin_amdgcn_readfirstlane(tid >> 6);  // filter group (wave-uniform)
    int px = tid & 63;
    int r = px >> 4;          // row in tile 0..3
    int c = px & 15;          // col in tile 0..15

    uint32_t acc[8];
    #pragma unroll
    for (int f = 0; f < 8; ++f) acc[f] = 0u;

    int lb = (r * 18 + c) * LSTRIDE;
    int t0 = fg << 1;                                 // rotation offset 0,2,4,6
    #pragma unroll 1
    for (int ti = 0; ti < 9; ++ti) {
        int t = t0 + ti;
        if (t >= 9) t -= 9;                           // rotated tap, wave-uniform
        int kh = (t * 11) >> 5;                       // == t/3 for t in [0,8]
        int kw = t - kh * 3;
        const uint4* p = (const uint4*)(sx + lb + (kh * 18 + kw) * LSTRIDE);
        uint4 x0 = p[0];
        uint4 x1 = p[1];
        // this tap's 8 filters: 256 B contiguous -> one s_load chunk
        const uint32_t* wt = qwp + (t * 32 + fg * 8) * 8;
        #pragma unroll
        for (int f = 0; f < 8; ++f) {
            const uint4* wp = (const uint4*)(wt + f * 8);
            uint4 wv0 = wp[0], wv1 = wp[1];
            uint32_t a = acc[f];
            a = sadu8(x0.x, wv0.x, a);
            a = sadu8(x0.y, wv0.y, a);
            a = sadu8(x0.z, wv0.z, a);
            a = sadu8(x0.w, wv0.w, a);
            a = sadu8(x1.x, wv1.x, a);
            a = sadu8(x1.y, wv1.y, a);
            a = sadu8(x1.z, wv1.z, a);
            a = sadu8(x1.w, wv1.w, a);
            acc[f] = a;
        }
    }

    size_t obase = (((size_t)n * 32 + fg * 8) * 16384) + (size_t)(h0 + r) * 128 + (w0 + c);
    #pragma unroll
    for (int f = 0; f < 8; ++f) {
        out[obase + (size_t)f * 16384] = -(float)acc[f] * INPUT_SCALE;
    }
}

extern "C" void kernel_launch(void* const* d_in, const int* in_sizes, int n_in,
                              void* d_out, int out_size, void* d_ws, size_t ws_size,
                              hipStream_t stream) {
    const float* x = (const float*)d_in[0];       // (16,32,128,128)
    const float* w = (const float*)d_in[1];       // (32,32,3,3)
    float* out = (float*)d_out;                   // (16,32,128,128)

    uint32_t* qwp = (uint32_t*)d_ws;              // 9216 B

    quant_weight<<<9, 256, 0, stream>>>(w, qwp);
    adder_conv_fused<<<4096, 256, 0, stream>>>(x, qwp, out);
}